// Round 2
// baseline (1955.224 us; speedup 1.0000x reference)
//
#include <hip/hip_runtime.h>

// 5-layer GRU, H=20, B=256, T=4096, fp32. PyTorch GRU math.
// One block per batch element; 5 waves per block = one wave per layer,
// wavefront-pipelined across chunks of K=16 timesteps.
//
// R1 restructure: lane i (0..19) owns ALL THREE gate rows (r,z,n) of hidden
// unit i, so the serial phase-B recurrence has NO ds_bpermute on the chain —
// only 20 v_readlane broadcasts + 60 local FMAs + clamp-free sigmoid/tanh.
// Cross-gate gathers of the input projections (xz, xn) are done in phase A
// with pipelined ds_bpermute (off the serial chain).

#define HH 20
#define GG 60
#define NL 5
#define BB 256
#define TT 4096
#define KK 16
#define NC (TT / KK)

struct Params {
  const float* x;
  const float* wih[NL];
  const float* whh[NL];
  const float* bih[NL];
  const float* bhh[NL];
  const float* wout;
  const float* bout;
  float* out;
};

__device__ __forceinline__ float bcast(float v, int j) {
  return __int_as_float(__builtin_amdgcn_readlane(__float_as_int(v), j));
}
__device__ __forceinline__ float shfl_idx(float v, int byteidx) {
  return __int_as_float(__builtin_amdgcn_ds_bpermute(byteidx, __float_as_int(v)));
}
// sigmoid(x) = 1/(1 + 2^(-x*log2e)); saturates cleanly (rcp(inf)=0), no clamp
__device__ __forceinline__ float fsig(float x) {
  float e = __builtin_amdgcn_exp2f(x * -1.442695041f);
  return __builtin_amdgcn_rcpf(1.0f + e);
}
// tanh(y) = 2*sigmoid(2y) - 1; saturates to +-1 without clamp
__device__ __forceinline__ float ftanh(float y) {
  float e = __builtin_amdgcn_exp2f(y * -2.885390082f);
  return fmaf(2.0f, __builtin_amdgcn_rcpf(1.0f + e), -1.0f);
}

__global__ __launch_bounds__(NL * 64) void gru5_kernel(Params p) {
  // layer->layer handoff, rows padded to 64 lanes so writes are unmasked
  __shared__ __align__(16) float hbuf[2][NL][KK][64];
  __shared__ float yp[NL];

  const int tid = threadIdx.x;
  const int l = tid >> 6;          // wave index == layer
  const int lane = tid & 63;
  const int b = blockIdx.x;
  const int g = lane < GG ? lane : GG - 1;   // phase-A gate owned by lane
  const int i = lane < HH ? lane : HH - 1;   // phase-B hidden unit (clamped)

  // ---- weights into registers ----
  float whh3[3 * HH];              // rows i, 20+i, 40+i of W_hh
  {
    const float* W = p.whh[l];
    #pragma unroll
    for (int gg = 0; gg < 3; ++gg)
      #pragma unroll
      for (int j = 0; j < HH; ++j)
        whh3[gg * HH + j] = W[(gg * HH + i) * HH + j];
  }
  const float bhn = p.bhh[l][2 * HH + i];    // n-gate hh-bias (inside r*(...))
  // fold b_ih (+ b_hh for r,z gates) into the phase-A projection
  const float bsum = p.bih[l][g] + (g < 2 * HH ? p.bhh[l][g] : 0.0f);
  float wih_r[HH];
  if (l == 0) {
    wih_r[0] = p.wih[0][g];
  } else {
    const float* W = p.wih[l];
    #pragma unroll
    for (int j = 0; j < HH; ++j) wih_r[j] = W[g * HH + j];
  }

  const int idx20 = ((lane + 20) & 63) << 2;   // bpermute byte indices
  const int idx40 = ((lane + 40) & 63) << 2;

  float hreg = 0.0f;               // lanes 0..19 carry h[i]
  float xr[KK], xz[KK], xn[KK], hlast[KK];

  const float* xrow = p.x + (size_t)b * TT;
  float* hout = p.out + (size_t)b * TT * HH;

  for (int s = 0; s < NC + NL - 1; ++s) {
    const int c = s - l;           // this wave's chunk (wave-uniform)
    if (c >= 0 && c < NC) {
      const int pr = (s + 1) & 1;  // read buffer
      const int pc = s & 1;        // write buffer

      // ---- phase A: input projections for the chunk (off-chain, full ILP) ----
      float xg[KK];
      if (l == 0) {
        const float4* xp = (const float4*)(xrow + c * KK);
        float4 xv[KK / 4];
        #pragma unroll
        for (int q = 0; q < KK / 4; ++q) xv[q] = xp[q];
        const float* xs = (const float*)xv;
        #pragma unroll
        for (int t = 0; t < KK; ++t) xg[t] = fmaf(wih_r[0], xs[t], bsum);
      } else {
        #pragma unroll
        for (int t = 0; t < KK; ++t) {
          float4 hv4[5];
          const float4* hin4 = (const float4*)(&hbuf[pr][l - 1][t][0]);
          #pragma unroll
          for (int q = 0; q < 5; ++q) hv4[q] = hin4[q];
          const float* hv = (const float*)hv4;
          float a0 = bsum, a1 = 0.f, a2 = 0.f, a3 = 0.f;
          #pragma unroll
          for (int j = 0; j < HH; j += 4) {
            a0 = fmaf(wih_r[j],     hv[j],     a0);
            a1 = fmaf(wih_r[j + 1], hv[j + 1], a1);
            a2 = fmaf(wih_r[j + 2], hv[j + 2], a2);
            a3 = fmaf(wih_r[j + 3], hv[j + 3], a3);
          }
          xg[t] = (a0 + a1) + (a2 + a3);
        }
      }
      // gather cross-gate projections to lane i (pipelined, off-chain)
      #pragma unroll
      for (int t = 0; t < KK; ++t) {
        xr[t] = xg[t];                         // r-row lives on lane i already
        xz[t] = shfl_idx(xg[t], idx20);        // z-gate projection (+biases)
        xn[t] = shfl_idx(xg[t], idx40);        // n-gate ih projection (+b_ih)
      }

      // ---- phase B: serial recurrence, no LDS/bpermute on the chain ----
      #pragma unroll
      for (int t = 0; t < KK; ++t) {
        float hs[HH];
        #pragma unroll
        for (int j = 0; j < HH; ++j) hs[j] = bcast(hreg, j);
        float r0 = xr[t], r1 = 0.f;
        float z0 = xz[t], z1 = 0.f;
        float n0 = bhn,   n1 = 0.f;
        #pragma unroll
        for (int j = 0; j < HH; j += 2) {
          r0 = fmaf(whh3[j],              hs[j],     r0);
          r1 = fmaf(whh3[j + 1],          hs[j + 1], r1);
          z0 = fmaf(whh3[HH + j],         hs[j],     z0);
          z1 = fmaf(whh3[HH + j + 1],     hs[j + 1], z1);
          n0 = fmaf(whh3[2 * HH + j],     hs[j],     n0);
          n1 = fmaf(whh3[2 * HH + j + 1], hs[j + 1], n1);
        }
        const float r = fsig(r0 + r1);
        const float z = fsig(z0 + z1);
        const float n = ftanh(fmaf(r, n0 + n1, xn[t]));
        hreg = fmaf(z, hreg - n, n);           // (1-z)*n + z*h
        hbuf[pc][l][t][lane] = hreg;           // unmasked, 2-way alias = free
        hlast[t] = hreg;
      }

      // ---- last layer: burst the chunk's h to global (one uniform branch) ----
      if (l == NL - 1 && lane < HH) {
        float* hp = hout + (size_t)c * KK * HH + lane;
        #pragma unroll
        for (int t = 0; t < KK; ++t) hp[(size_t)t * HH] = hlast[t];
      }

      // ---- epilogue at last chunk: h_n + y_hat partial ----
      if (c == NC - 1) {
        if (lane < HH)
          p.out[(size_t)BB * TT * HH + (size_t)b * NL * HH + l * HH + lane] = hreg;
        float pp = (lane < HH) ? hreg * p.wout[l * HH + lane] : 0.0f;
        #pragma unroll
        for (int off = 32; off > 0; off >>= 1) pp += __shfl_down(pp, off);
        if (lane == 0) yp[l] = pp;
      }
    }
    __syncthreads();
  }

  if (tid == 0) {
    float y = p.bout[0];
    #pragma unroll
    for (int ll = 0; ll < NL; ++ll) y += yp[ll];
    p.out[(size_t)BB * TT * HH + (size_t)BB * NL * HH + b] = y;
  }
}

extern "C" void kernel_launch(void* const* d_in, const int* in_sizes, int n_in,
                              void* d_out, int out_size, void* d_ws, size_t ws_size,
                              hipStream_t stream) {
  Params p;
  p.x = (const float*)d_in[0];
  for (int l = 0; l < NL; ++l) {
    p.wih[l] = (const float*)d_in[1 + 4 * l];
    p.whh[l] = (const float*)d_in[2 + 4 * l];
    p.bih[l] = (const float*)d_in[3 + 4 * l];
    p.bhh[l] = (const float*)d_in[4 + 4 * l];
  }
  p.wout = (const float*)d_in[1 + 4 * NL];
  p.bout = (const float*)d_in[2 + 4 * NL];
  p.out = (float*)d_out;

  gru5_kernel<<<BB, NL * 64, 0, stream>>>(p);
}

// Round 3
// 1295.487 us; speedup vs baseline: 1.5093x; 1.5093x over previous
//
#include <hip/hip_runtime.h>

// 5-layer GRU, H=20, B=256, T=4096, fp32. PyTorch GRU math.
// One block per batch element; 5 waves = one per layer, pipelined over
// KK=16-timestep chunks.
//
// R2: back to R0's 60-lane mapping (lane g owns gate g: 20-FMA matvec, 94%
// lane efficiency). NEW: the producer wave computes the NEXT layer's input
// projection using the h-broadcast SGPRs it already has (xnext, +20 FMA/t,
// no cross-lane) — the consumer's phase A (20 FMA/t + 80 broadcast b128
// LDS reads/chunk) disappears. On-chain cross-lane reduced to 2 bpermutes/t
// (sz from lane+20, ghn from lane+40); the xn column is pre-read off-chain.

#define HH 20
#define GG 60
#define NL 5
#define BB 256
#define TT 4096
#define KK 16
#define NC (TT / KK)

struct Params {
  const float* x;
  const float* wih[NL];
  const float* whh[NL];
  const float* bih[NL];
  const float* bhh[NL];
  const float* wout;
  const float* bout;
  float* out;
};

__device__ __forceinline__ float bcast(float v, int j) {
  return __int_as_float(__builtin_amdgcn_readlane(__float_as_int(v), j));
}
__device__ __forceinline__ float shfl_idx(float v, int byteidx) {
  return __int_as_float(__builtin_amdgcn_ds_bpermute(byteidx, __float_as_int(v)));
}
// sigmoid(x) = 1/(1 + 2^(-x*log2e)); saturates cleanly (rcp(inf)=0)
__device__ __forceinline__ float fsig(float x) {
  float e = __builtin_amdgcn_exp2f(x * -1.442695041f);
  return __builtin_amdgcn_rcpf(1.0f + e);
}
// tanh(y) = 2*sigmoid(2y) - 1; saturates to +-1 without clamp
__device__ __forceinline__ float ftanh(float y) {
  float e = __builtin_amdgcn_exp2f(y * -2.885390082f);
  return fmaf(2.0f, __builtin_amdgcn_rcpf(1.0f + e), -1.0f);
}

__global__ __launch_bounds__(NL * 64) void gru5_kernel(Params p) {
  // xg handoff: producer layer l (0..3) writes slot l; consumer l+1 reads.
  // [t][64] layout: per-t write is lane==column (conflict-free), column
  // reads are stride-64 b32 (2-way alias = free).
  __shared__ float xbuf[2][NL - 1][KK][64];
  __shared__ float yp[NL];

  const int tid = threadIdx.x;
  const int l = tid >> 6;          // wave index == layer
  const int lane = tid & 63;
  const int b = blockIdx.x;
  const int g = lane < GG ? lane : GG - 1;            // gate owned by lane
  const int gn = lane < HH ? lane + 2 * HH : GG - 1;  // n-gate column for unit lane

  // ---- weights into registers ----
  float whh_r[HH];
  {
    const float* W = p.whh[l];
    #pragma unroll
    for (int j = 0; j < HH; ++j) whh_r[j] = W[g * HH + j];
  }
  // hh accumulator init: b_hh only for n-gate rows (r/z b_hh folded into xg)
  const float binit = (g >= 2 * HH) ? p.bhh[l][g] : 0.0f;

  // producer weights: next layer's ih row for gate g (+ folded biases)
  float wnx[HH];
  float bnx = 0.0f;
  if (l < NL - 1) {
    const float* W = p.wih[l + 1];
    #pragma unroll
    for (int j = 0; j < HH; ++j) wnx[j] = W[g * HH + j];
    bnx = p.bih[l + 1][g] + (g < 2 * HH ? p.bhh[l + 1][g] : 0.0f);
  }
  // layer 0: scalar input weights (own gate + the n-gate of unit `lane`)
  float w0own = 0.f, b0own = 0.f, w0n = 0.f, b0n = 0.f;
  if (l == 0) {
    w0own = p.wih[0][g];
    b0own = p.bih[0][g] + (g < 2 * HH ? p.bhh[0][g] : 0.0f);
    w0n = p.wih[0][gn];
    b0n = p.bih[0][gn];               // b_ih only (b_hh_n stays in binit)
  }

  const int idx20 = ((lane + 20) & 63) << 2;   // bpermute byte indices
  const int idx40 = ((lane + 40) & 63) << 2;

  float hreg = 0.0f;               // lanes 0..19 carry h[unit]
  float xr_a[KK], xn_a[KK], hlast[KK];

  const float* xrow = p.x + (size_t)b * TT;
  float* hout = p.out + (size_t)b * TT * HH;

  for (int s = 0; s < NC + NL - 1; ++s) {
    const int c = s - l;           // this wave's chunk (wave-uniform)
    if (c >= 0 && c < NC) {
      const int pr = (s + 1) & 1;  // read buffer
      const int pc = s & 1;        // write buffer

      // ---- chunk-start: fetch this chunk's input projections ----
      if (l == 0) {
        const float4* xp = (const float4*)(xrow + c * KK);
        float4 xv[KK / 4];
        #pragma unroll
        for (int q = 0; q < KK / 4; ++q) xv[q] = xp[q];
        const float* xs = (const float*)xv;
        #pragma unroll
        for (int t = 0; t < KK; ++t) {
          xr_a[t] = fmaf(w0own, xs[t], b0own);   // own gate's x-projection
          xn_a[t] = fmaf(w0n, xs[t], b0n);       // n-gate x-projection (unit lane)
        }
      } else {
        const float* src = &xbuf[pr][l - 1][0][0];
        #pragma unroll
        for (int t = 0; t < KK; ++t) {
          xr_a[t] = src[t * 64 + g];             // own gate column
          xn_a[t] = src[t * 64 + gn];            // n-gate column
        }
      }

      // ---- fused recurrence + next-layer projection ----
      // iter t: readlane h_{t-1}; hh-matvec+update for t; xnext for t-1
      // (both consume the same h_{t-1} broadcast).
      #pragma unroll
      for (int t = 0; t <= KK; ++t) {
        float hs[HH];
        #pragma unroll
        for (int j = 0; j < HH; ++j) hs[j] = bcast(hreg, j);

        if (t < KK) {
          float a0 = binit, a1 = 0.f, a2 = 0.f, a3 = 0.f;
          #pragma unroll
          for (int j = 0; j < HH; j += 4) {
            a0 = fmaf(whh_r[j],     hs[j],     a0);
            a1 = fmaf(whh_r[j + 1], hs[j + 1], a1);
            a2 = fmaf(whh_r[j + 2], hs[j + 2], a2);
            a3 = fmaf(whh_r[j + 3], hs[j + 3], a3);
          }
          const float gh = (a0 + a1) + (a2 + a3);   // (W_hh h)[g] (+b_hh_n)
          const float sv = xr_a[t] + gh;            // full preact (r/z rows)
          const float szn = shfl_idx(sv, idx20);    // z preact for unit lane
          const float ghn = shfl_idx(gh, idx40);    // n-gate h-proj (+b_hh_n)
          const float r = fsig(sv);
          const float z = fsig(szn);
          const float n = ftanh(fmaf(r, ghn, xn_a[t]));
          hreg = fmaf(z, hreg - n, n);              // (1-z)*n + z*h
          hlast[t] = hreg;
        }
        if (t > 0 && l < NL - 1) {
          float b0 = bnx, b1 = 0.f;
          #pragma unroll
          for (int j = 0; j < HH; j += 2) {
            b0 = fmaf(wnx[j],     hs[j],     b0);
            b1 = fmaf(wnx[j + 1], hs[j + 1], b1);
          }
          xbuf[pc][l][t - 1][lane] = b0 + b1;       // next layer's xg[t-1][g]
        }
      }

      // ---- last layer: burst h to global ----
      if (l == NL - 1 && lane < HH) {
        float* hp = hout + (size_t)c * KK * HH + lane;
        #pragma unroll
        for (int t = 0; t < KK; ++t) hp[(size_t)t * HH] = hlast[t];
      }

      // ---- epilogue at last chunk: h_n + y_hat partial ----
      if (c == NC - 1) {
        if (lane < HH)
          p.out[(size_t)BB * TT * HH + (size_t)b * NL * HH + l * HH + lane] = hreg;
        float pp = (lane < HH) ? hreg * p.wout[l * HH + lane] : 0.0f;
        #pragma unroll
        for (int off = 32; off > 0; off >>= 1) pp += __shfl_down(pp, off);
        if (lane == 0) yp[l] = pp;
      }
    }
    __syncthreads();
  }

  if (tid == 0) {
    float y = p.bout[0];
    #pragma unroll
    for (int ll = 0; ll < NL; ++ll) y += yp[ll];
    p.out[(size_t)BB * TT * HH + (size_t)BB * NL * HH + b] = y;
  }
}

extern "C" void kernel_launch(void* const* d_in, const int* in_sizes, int n_in,
                              void* d_out, int out_size, void* d_ws, size_t ws_size,
                              hipStream_t stream) {
  Params p;
  p.x = (const float*)d_in[0];
  for (int l = 0; l < NL; ++l) {
    p.wih[l] = (const float*)d_in[1 + 4 * l];
    p.whh[l] = (const float*)d_in[2 + 4 * l];
    p.bih[l] = (const float*)d_in[3 + 4 * l];
    p.bhh[l] = (const float*)d_in[4 + 4 * l];
  }
  p.wout = (const float*)d_in[1 + 4 * NL];
  p.bout = (const float*)d_in[2 + 4 * NL];
  p.out = (float*)d_out;

  gru5_kernel<<<BB, NL * 64, 0, stream>>>(p);
}

// Round 4
// 1293.077 us; speedup vs baseline: 1.5121x; 1.0019x over previous
//
#include <hip/hip_runtime.h>

// 5-layer GRU, H=20, B=256, T=4096, fp32. PyTorch GRU math.
// One block per batch element; 5 waves = one per layer, pipelined over
// KK=16-timestep chunks.
//
// R2: lane g owns gate g (20-FMA hh matvec, 94% lane efficiency); producer
// wave computes the next layer's input projection (xnext) from the h-broadcast
// SGPRs it already holds; 2 on-chain bpermutes/t (z preact, n h-proj).
//
// R3: __launch_bounds__(320, 1). We run exactly 1 block/CU (256 blocks on
// 256 CUs), so occupancy >1 block is useless — without this the compiler
// capped VGPRs at ~56 and SANK the loop-invariant weight loads into the
// t-loop (20+ L1 reloads + vmcnt waits per timestep ON the serial chain).
// R2 counters: VGPR_Count=56 < the ~88 live floats the source needs.

#define HH 20
#define GG 60
#define NL 5
#define BB 256
#define TT 4096
#define KK 16
#define NC (TT / KK)

struct Params {
  const float* x;
  const float* wih[NL];
  const float* whh[NL];
  const float* bih[NL];
  const float* bhh[NL];
  const float* wout;
  const float* bout;
  float* out;
};

__device__ __forceinline__ float bcast(float v, int j) {
  return __int_as_float(__builtin_amdgcn_readlane(__float_as_int(v), j));
}
__device__ __forceinline__ float shfl_idx(float v, int byteidx) {
  return __int_as_float(__builtin_amdgcn_ds_bpermute(byteidx, __float_as_int(v)));
}
// sigmoid(x) = 1/(1 + 2^(-x*log2e)); saturates cleanly (rcp(inf)=0)
__device__ __forceinline__ float fsig(float x) {
  float e = __builtin_amdgcn_exp2f(x * -1.442695041f);
  return __builtin_amdgcn_rcpf(1.0f + e);
}
// tanh(y) = 2*sigmoid(2y) - 1; saturates to +-1 without clamp
__device__ __forceinline__ float ftanh(float y) {
  float e = __builtin_amdgcn_exp2f(y * -2.885390082f);
  return fmaf(2.0f, __builtin_amdgcn_rcpf(1.0f + e), -1.0f);
}

__global__ __launch_bounds__(NL * 64, 1) void gru5_kernel(Params p) {
  // xg handoff: producer layer l (0..3) writes slot l; consumer l+1 reads.
  // [t][64] layout: per-t write is lane==column (conflict-free), column
  // reads are stride-64 b32 (2-way alias = free).
  __shared__ float xbuf[2][NL - 1][KK][64];
  __shared__ float yp[NL];

  const int tid = threadIdx.x;
  const int l = tid >> 6;          // wave index == layer
  const int lane = tid & 63;
  const int b = blockIdx.x;
  const int g = lane < GG ? lane : GG - 1;            // gate owned by lane
  const int gn = lane < HH ? lane + 2 * HH : GG - 1;  // n-gate column for unit lane

  // ---- weights into registers (register-resident: launch_bounds(.,1)) ----
  float whh_r[HH];
  {
    const float* W = p.whh[l];
    #pragma unroll
    for (int j = 0; j < HH; ++j) whh_r[j] = W[g * HH + j];
  }
  // hh accumulator init: b_hh only for n-gate rows (r/z b_hh folded into xg)
  const float binit = (g >= 2 * HH) ? p.bhh[l][g] : 0.0f;

  // producer weights: next layer's ih row for gate g (+ folded biases)
  float wnx[HH];
  float bnx = 0.0f;
  if (l < NL - 1) {
    const float* W = p.wih[l + 1];
    #pragma unroll
    for (int j = 0; j < HH; ++j) wnx[j] = W[g * HH + j];
    bnx = p.bih[l + 1][g] + (g < 2 * HH ? p.bhh[l + 1][g] : 0.0f);
  }
  // layer 0: scalar input weights (own gate + the n-gate of unit `lane`)
  float w0own = 0.f, b0own = 0.f, w0n = 0.f, b0n = 0.f;
  if (l == 0) {
    w0own = p.wih[0][g];
    b0own = p.bih[0][g] + (g < 2 * HH ? p.bhh[0][g] : 0.0f);
    w0n = p.wih[0][gn];
    b0n = p.bih[0][gn];               // b_ih only (b_hh_n stays in binit)
  }

  const int idx20 = ((lane + 20) & 63) << 2;   // bpermute byte indices
  const int idx40 = ((lane + 40) & 63) << 2;

  float hreg = 0.0f;               // lanes 0..19 carry h[unit]
  float xr_a[KK], xn_a[KK], hlast[KK];

  const float* xrow = p.x + (size_t)b * TT;
  float* hout = p.out + (size_t)b * TT * HH;

  for (int s = 0; s < NC + NL - 1; ++s) {
    const int c = s - l;           // this wave's chunk (wave-uniform)
    if (c >= 0 && c < NC) {
      const int pr = (s + 1) & 1;  // read buffer
      const int pc = s & 1;        // write buffer

      // ---- chunk-start: fetch this chunk's input projections ----
      if (l == 0) {
        const float4* xp = (const float4*)(xrow + c * KK);
        float4 xv[KK / 4];
        #pragma unroll
        for (int q = 0; q < KK / 4; ++q) xv[q] = xp[q];
        const float* xs = (const float*)xv;
        #pragma unroll
        for (int t = 0; t < KK; ++t) {
          xr_a[t] = fmaf(w0own, xs[t], b0own);   // own gate's x-projection
          xn_a[t] = fmaf(w0n, xs[t], b0n);       // n-gate x-projection (unit lane)
        }
      } else {
        const float* src = &xbuf[pr][l - 1][0][0];
        #pragma unroll
        for (int t = 0; t < KK; ++t) {
          xr_a[t] = src[t * 64 + g];             // own gate column
          xn_a[t] = src[t * 64 + gn];            // n-gate column
        }
      }

      // ---- fused recurrence + next-layer projection ----
      // iter t: readlane h_{t-1}; hh-matvec+update for t; xnext for t-1
      // (both consume the same h_{t-1} broadcast).
      #pragma unroll
      for (int t = 0; t <= KK; ++t) {
        float hs[HH];
        #pragma unroll
        for (int j = 0; j < HH; ++j) hs[j] = bcast(hreg, j);

        if (t < KK) {
          float a0 = binit, a1 = 0.f, a2 = 0.f, a3 = 0.f;
          #pragma unroll
          for (int j = 0; j < HH; j += 4) {
            a0 = fmaf(whh_r[j],     hs[j],     a0);
            a1 = fmaf(whh_r[j + 1], hs[j + 1], a1);
            a2 = fmaf(whh_r[j + 2], hs[j + 2], a2);
            a3 = fmaf(whh_r[j + 3], hs[j + 3], a3);
          }
          const float gh = (a0 + a1) + (a2 + a3);   // (W_hh h)[g] (+b_hh_n)
          const float sv = xr_a[t] + gh;            // full preact (r/z rows)
          const float szn = shfl_idx(sv, idx20);    // z preact for unit lane
          const float ghn = shfl_idx(gh, idx40);    // n-gate h-proj (+b_hh_n)
          const float r = fsig(sv);
          const float z = fsig(szn);
          const float n = ftanh(fmaf(r, ghn, xn_a[t]));
          hreg = fmaf(z, hreg - n, n);              // (1-z)*n + z*h
          hlast[t] = hreg;
        }
        if (t > 0 && l < NL - 1) {
          float b0 = bnx, b1 = 0.f;
          #pragma unroll
          for (int j = 0; j < HH; j += 2) {
            b0 = fmaf(wnx[j],     hs[j],     b0);
            b1 = fmaf(wnx[j + 1], hs[j + 1], b1);
          }
          xbuf[pc][l][t - 1][lane] = b0 + b1;       // next layer's xg[t-1][g]
        }
      }

      // ---- last layer: burst h to global ----
      if (l == NL - 1 && lane < HH) {
        float* hp = hout + (size_t)c * KK * HH + lane;
        #pragma unroll
        for (int t = 0; t < KK; ++t) hp[(size_t)t * HH] = hlast[t];
      }

      // ---- epilogue at last chunk: h_n + y_hat partial ----
      if (c == NC - 1) {
        if (lane < HH)
          p.out[(size_t)BB * TT * HH + (size_t)b * NL * HH + l * HH + lane] = hreg;
        float pp = (lane < HH) ? hreg * p.wout[l * HH + lane] : 0.0f;
        #pragma unroll
        for (int off = 32; off > 0; off >>= 1) pp += __shfl_down(pp, off);
        if (lane == 0) yp[l] = pp;
      }
    }
    __syncthreads();
  }

  if (tid == 0) {
    float y = p.bout[0];
    #pragma unroll
    for (int ll = 0; ll < NL; ++ll) y += yp[ll];
    p.out[(size_t)BB * TT * HH + (size_t)BB * NL * HH + b] = y;
  }
}

extern "C" void kernel_launch(void* const* d_in, const int* in_sizes, int n_in,
                              void* d_out, int out_size, void* d_ws, size_t ws_size,
                              hipStream_t stream) {
  Params p;
  p.x = (const float*)d_in[0];
  for (int l = 0; l < NL; ++l) {
    p.wih[l] = (const float*)d_in[1 + 4 * l];
    p.whh[l] = (const float*)d_in[2 + 4 * l];
    p.bih[l] = (const float*)d_in[3 + 4 * l];
    p.bhh[l] = (const float*)d_in[4 + 4 * l];
  }
  p.wout = (const float*)d_in[1 + 4 * NL];
  p.bout = (const float*)d_in[2 + 4 * NL];
  p.out = (float*)d_out;

  gru5_kernel<<<BB, NL * 64, 0, stream>>>(p);
}